// Round 7
// baseline (37963.220 us; speedup 1.0000x reference)
//
#include <hip/hip_runtime.h>

// MatchLSTM forward (Round 7) = Round 6 + wide weight loads.
// Round-6 counters: phaseB 61 us/step, VALUBusy 19%, HBM 1% -> latency-bound
// on single-dword weight loads (~4 x 256B outstanding/wave vs ~500cy LLC).
// Fix: bf16 weights repacked as uint4 [h/8][j] (16B/lane, 1KB/wave-load),
// inner loops stage 16-24 loads in registers per chunk -> ~32KB in flight
// per SIMD -> BW-bound instead of latency-bound.
//
// Structure: phase B independent per batch element (one block per b, state
// in LDS, no grid sync). Phase A = 5 fp32 tiled GEMMs (unchanged).

#define DEV static __device__ __forceinline__

DEV float fast_sigmoid(float x) { return 1.0f / (1.0f + __expf(-x)); }
DEV float fast_tanh(float x)    { return 1.0f - 2.0f / (__expf(2.0f * x) + 1.0f); }

// bf16 pack/unpack (RTNE pack; unpack = shift into fp32 exponent position)
DEV unsigned f2bf(float x) {
    unsigned v = __float_as_uint(x);
    return (v + 0x7FFFu + ((v >> 16) & 1u)) >> 16;
}
DEV float blo(unsigned u) { return __uint_as_float(u << 16); }
DEV float bhi(unsigned u) { return __uint_as_float(u & 0xFFFF0000u); }

// ---------------------------------------------------------------------------
// Phase A GEMM (unchanged from Round 1; verified passing).
// ---------------------------------------------------------------------------
template<int BM, int NG, int MODE, int GATHER>
__global__ __launch_bounds__(256) void gemm3_kernel(
    const float* __restrict__ A, const int* __restrict__ gidx, int lda,
    const float* __restrict__ W, int ldw, int K,
    const float* __restrict__ bias1, const float* __restrict__ bias2,
    const float* __restrict__ add3, float* __restrict__ out)
{
    constexpr int BK = 32;
    constexpr int TM = BM / 16;
    constexpr int TJ = 2;
    constexpr int AP = BM + 4;
    constexpr int WP = NG * 32 + 4;
    __shared__ __align__(16) float As[BK][AP];
    __shared__ __align__(16) float Wsh[BK][WP];

    const int tid = threadIdx.x;
    const int ty = tid >> 4;
    const int tx = tid & 15;
    const int m0 = blockIdx.x * BM;
    const int j0 = blockIdx.y * 32;

    float acc[TM][TJ][NG];
#pragma unroll
    for (int im = 0; im < TM; ++im)
#pragma unroll
        for (int ij = 0; ij < TJ; ++ij)
#pragma unroll
            for (int g = 0; g < NG; ++g) acc[im][ij][g] = 0.0f;

    for (int k0 = 0; k0 < K; k0 += BK) {
#pragma unroll
        for (int i = tid; i < BM * BK; i += 256) {
            int r = i >> 5, c = i & 31;
            int gk = k0 + c;
            float v = 0.0f;
            if (gk < K) {
                int arow = GATHER ? gidx[m0 + r] : (m0 + r);
                v = A[arow * lda + gk];
            }
            As[c][r] = v;
        }
#pragma unroll
        for (int i = tid; i < NG * 32 * BK; i += 256) {
            int rl = i >> 5, c = i & 31;
            int g = rl >> 5, jj = rl & 31;
            int row = (g == 0 ? 0 : (g == 1 ? 1024 : 1536)) + j0 + jj;
            int gk = k0 + c;
            float v = (gk < K) ? W[row * ldw + gk] : 0.0f;
            Wsh[c][rl] = v;
        }
        __syncthreads();
#pragma unroll
        for (int kk = 0; kk < BK; ++kk) {
            float av[TM];
            if constexpr (TM == 4) {
                float4 t4 = *reinterpret_cast<const float4*>(&As[kk][ty * 4]);
                av[0] = t4.x; av[1] = t4.y; av[2] = t4.z; av[3] = t4.w;
            } else {
                float2 t2 = *reinterpret_cast<const float2*>(&As[kk][ty * 2]);
                av[0] = t2.x; av[1] = t2.y;
            }
#pragma unroll
            for (int g = 0; g < NG; ++g) {
                float2 w2 = *reinterpret_cast<const float2*>(&Wsh[kk][g * 32 + tx * 2]);
#pragma unroll
                for (int im = 0; im < TM; ++im) {
                    acc[im][0][g] += av[im] * w2.x;
                    acc[im][1][g] += av[im] * w2.y;
                }
            }
        }
        __syncthreads();
    }

#pragma unroll
    for (int im = 0; im < TM; ++im) {
        int m = m0 + ty * TM + im;
#pragma unroll
        for (int ij = 0; ij < TJ; ++ij) {
            int j = j0 + tx * TJ + ij;
            if constexpr (MODE == 3) {
                out[m * 512 + j] = acc[im][ij][0];
            } else if constexpr (MODE == 1) {
                out[(m * 3 + 0) * 512 + j] = acc[im][ij][0] + bias1[j] + bias2[j];
                out[(m * 3 + 1) * 512 + j] = acc[im][ij][1] + bias1[1024 + j] + bias2[1024 + j];
                out[(m * 3 + 2) * 512 + j] = acc[im][ij][2] + bias1[1536 + j] + bias2[1536 + j];
            } else if constexpr (MODE == 0) {
                float gi = acc[im][ij][0] + bias1[j] + bias2[j];
                float gg = acc[im][ij][1] + bias1[1024 + j] + bias2[1024 + j];
                float go = acc[im][ij][2] + bias1[1536 + j] + bias2[1536 + j];
                float c  = fast_sigmoid(gi) * fast_tanh(gg);
                out[m * 512 + j] = fast_sigmoid(go) * fast_tanh(c);
            } else {
                float gi = acc[im][ij][0] + add3[(m * 3 + 0) * 512 + j];
                float gg = acc[im][ij][1] + add3[(m * 3 + 1) * 512 + j];
                float go = acc[im][ij][2] + add3[(m * 3 + 2) * 512 + j];
                float c  = fast_sigmoid(gi) * fast_tanh(gg);
                out[m * 512 + j] = fast_sigmoid(go) * fast_tanh(c);
            }
        }
    }
}

// ---------------------------------------------------------------------------
// Transpose + bf16-pack into uint4-friendly layout:
//   conceptually uint4 Wpk[h/8][cols]; element [hq][col] packs
//   W[col][8hq..8hq+7] as 4 dwords of bf16 pairs (lo = even h, hi = odd h).
// dword index for pair q=(h/2), col: (q>>2)*(4*out_ld) + 4*col + (q&3).
// gates=0: Wm (cols=512). gates=1: blockIdx.z picks gate row-base
// {0,1024,1536} of Wih_m (a-half cols 0..511), out col block z*512 (out_ld=1536).
// ---------------------------------------------------------------------------
__global__ __launch_bounds__(256) void trans_pack_kernel(
    const float* __restrict__ W, int ld, int gates,
    unsigned* __restrict__ out, int out_ld)
{
    __shared__ float tile[64][129];
    const int j0 = blockIdx.x * 64;
    const int h0 = blockIdx.y * 128;
    const int g  = blockIdx.z;
    const int row_base = gates ? (g == 0 ? 0 : (g == 1 ? 1024 : 1536)) : 0;
    const int out_col  = gates ? g * 512 : 0;

    for (int i = threadIdx.x; i < 64 * 128; i += 256) {
        int jj = i >> 7, hh = i & 127;
        tile[jj][hh] = W[(size_t)(row_base + j0 + jj) * ld + h0 + hh];
    }
    __syncthreads();
    for (int i = threadIdx.x; i < 4096; i += 256) {
        int jj = i & 63, q = i >> 6;                      // q in [0,64) local
        int gq = h0 / 2 + q;                              // global pair index
        unsigned lo = f2bf(tile[jj][2 * q]);
        unsigned hi = f2bf(tile[jj][2 * q + 1]);
        int col = out_col + j0 + jj;
        out[(size_t)(gq >> 2) * (4 * out_ld) + 4 * col + (gq & 3)] = lo | (hi << 16);
    }
}

// ---------------------------------------------------------------------------
// Phase B: one block per batch element b, 512 threads, 64 steps, NO grid sync.
// Weight GEMVs read uint4-packed bf16 (16B/lane), staged 16-24 deep in
// registers to keep ~32KB/SIMD of loads in flight (latency -> BW bound).
// ---------------------------------------------------------------------------
__global__ __launch_bounds__(512, 2) void phaseB_kernel(
    const float* __restrict__ pre_s, const float* __restrict__ pre_t,
    const float* __restrict__ h_s,   const float* __restrict__ pre_m_h,
    const unsigned* __restrict__ WmT2, const unsigned* __restrict__ W3t2,
    const float* __restrict__ w_e,
    const float* __restrict__ fc_w,  const float* __restrict__ fc_b,
    float* __restrict__ out)
{
    __shared__ __align__(16) float hm[512];
    __shared__ __align__(16) float av[512];
    __shared__ __align__(16) float base[512];
    __shared__ __align__(16) float wesh[512];
    __shared__ __align__(16) float sc[64];

    const int b    = blockIdx.x;
    const int tid  = threadIdx.x;          // 0..511
    const int wv   = tid >> 6;             // 0..7
    const int lane = tid & 63;

    wesh[tid] = w_e[tid];
    hm[tid]   = 0.0f;
    __syncthreads();

    const uint4* wpm = (const uint4*)WmT2 + tid;   // [64][512] uint4 view
    const uint4* wp3 = (const uint4*)W3t2 + tid;   // [64][1536] uint4 view

    for (int k = 0; k < 64; ++k) {
        // ---- wm[j=tid] = sum_h hm[h] * Wm[j][h]  (uint4 bf16, 16-deep) ----
        float wmj = 0.0f;
        if (k > 0) {
#pragma unroll
            for (int hq0 = 0; hq0 < 64; hq0 += 16) {
                uint4 u[16];
#pragma unroll
                for (int z = 0; z < 16; ++z) u[z] = wpm[(size_t)(hq0 + z) * 512];
#pragma unroll
                for (int z = 0; z < 16; ++z) {
                    float4 hA = *(const float4*)&hm[(hq0 + z) * 8];
                    float4 hB = *(const float4*)&hm[(hq0 + z) * 8 + 4];
                    wmj += blo(u[z].x) * hA.x + bhi(u[z].x) * hA.y
                         + blo(u[z].y) * hA.z + bhi(u[z].y) * hA.w
                         + blo(u[z].z) * hB.x + bhi(u[z].z) * hB.y
                         + blo(u[z].w) * hB.z + bhi(u[z].w) * hB.w;
                }
            }
        }
        base[tid] = pre_t[((size_t)k * 128 + b) * 512 + tid] + wmj;
        __syncthreads();

        // ---- scores[t] = sum_h w_e[h] * tanh(pre_s[t,b,h] + base[h]) ----
        for (int tt = 0; tt < 8; ++tt) {
            int t = wv * 8 + tt;
            const float* ps = pre_s + ((size_t)t * 128 + b) * 512;
            float p = 0.0f;
#pragma unroll
            for (int u = 0; u < 8; ++u) {
                int h = lane + 64 * u;
                p += wesh[h] * fast_tanh(ps[h] + base[h]);
            }
#pragma unroll
            for (int off = 32; off; off >>= 1) p += __shfl_xor(p, off);
            if (lane == 0) sc[t] = p;
        }
        __syncthreads();
        if (wv == 0) {                      // softmax over 64 t
            float s = sc[lane], mx = s;
#pragma unroll
            for (int off = 32; off; off >>= 1) mx = fmaxf(mx, __shfl_xor(mx, off));
            float e = __expf(s - mx), sum = e;
#pragma unroll
            for (int off = 32; off; off >>= 1) sum += __shfl_xor(sum, off);
            sc[lane] = e / sum;
        }
        __syncthreads();

        // ---- a[h=tid] = sum_t alpha[t] * h_s[t,b,h] ----
        {
            float aacc = 0.0f;
            const float* hp = h_s + (size_t)b * 512 + tid;
#pragma unroll
            for (int t4 = 0; t4 < 16; ++t4) {
                float4 s4 = *(const float4*)&sc[t4 * 4];
                aacc += s4.x * hp[(size_t)(t4 * 4 + 0) * 65536]
                      + s4.y * hp[(size_t)(t4 * 4 + 1) * 65536]
                      + s4.z * hp[(size_t)(t4 * 4 + 2) * 65536]
                      + s4.w * hp[(size_t)(t4 * 4 + 3) * 65536];
            }
            av[tid] = aacc;
        }
        __syncthreads();

        // ---- gates: gi/gg/go[j=tid] = sum_k a[k] * Wih_m[grow+j][k] ----
        float gi = 0.0f, gg = 0.0f, go = 0.0f;
#pragma unroll
        for (int hq0 = 0; hq0 < 64; hq0 += 8) {
            uint4 ui[8], ug[8], uo[8];
#pragma unroll
            for (int z = 0; z < 8; ++z) {
                ui[z] = wp3[(size_t)(hq0 + z) * 1536];
                ug[z] = wp3[(size_t)(hq0 + z) * 1536 + 512];
                uo[z] = wp3[(size_t)(hq0 + z) * 1536 + 1024];
            }
#pragma unroll
            for (int z = 0; z < 8; ++z) {
                float4 aA = *(const float4*)&av[(hq0 + z) * 8];
                float4 aB = *(const float4*)&av[(hq0 + z) * 8 + 4];
                gi += blo(ui[z].x) * aA.x + bhi(ui[z].x) * aA.y
                    + blo(ui[z].y) * aA.z + bhi(ui[z].y) * aA.w
                    + blo(ui[z].z) * aB.x + bhi(ui[z].z) * aB.y
                    + blo(ui[z].w) * aB.z + bhi(ui[z].w) * aB.w;
                gg += blo(ug[z].x) * aA.x + bhi(ug[z].x) * aA.y
                    + blo(ug[z].y) * aA.z + bhi(ug[z].y) * aA.w
                    + blo(ug[z].z) * aB.x + bhi(ug[z].z) * aB.y
                    + blo(ug[z].w) * aB.z + bhi(ug[z].w) * aB.w;
                go += blo(uo[z].x) * aA.x + bhi(uo[z].x) * aA.y
                    + blo(uo[z].y) * aA.z + bhi(uo[z].y) * aA.w
                    + blo(uo[z].z) * aB.x + bhi(uo[z].z) * aB.y
                    + blo(uo[z].w) * aB.z + bhi(uo[z].w) * aB.w;
            }
        }
        const size_t m = (size_t)k * 128 + b;
        gi += pre_m_h[(m * 3 + 0) * 512 + tid];
        gg += pre_m_h[(m * 3 + 1) * 512 + tid];
        go += pre_m_h[(m * 3 + 2) * 512 + tid];
        float cc   = fast_sigmoid(gi) * fast_tanh(gg);
        float hnew = fast_sigmoid(go) * fast_tanh(cc);
        __syncthreads();
        hm[tid] = hnew;
        __syncthreads();
    }

    // ---- FC epilogue: out[b,c] = hm . fc_w[c] + fc_b[c], waves 0..2 ----
    if (wv < 3) {
        float p = 0.0f;
#pragma unroll
        for (int u = 0; u < 8; ++u) {
            int h = lane + 64 * u;
            p += hm[h] * fc_w[wv * 512 + h];
        }
#pragma unroll
        for (int off = 32; off; off >>= 1) p += __shfl_xor(p, off);
        if (lane == 0) out[b * 3 + wv] = p + fc_b[wv];
    }
}

extern "C" void kernel_launch(void* const* d_in, const int* in_sizes, int n_in,
                              void* d_out, int out_size, void* d_ws, size_t ws_size,
                              hipStream_t stream)
{
    (void)in_sizes; (void)n_in; (void)out_size;
    const int*   premise    = (const int*)d_in[0];
    const int*   hypothesis = (const int*)d_in[2];
    const float* embed  = (const float*)d_in[4];
    const float* w_e    = (const float*)d_in[5];
    const float* Ws     = (const float*)d_in[6];
    const float* Wt     = (const float*)d_in[7];
    const float* Wm     = (const float*)d_in[8];
    const float* Wih_p  = (const float*)d_in[9];
    const float* bih_p  = (const float*)d_in[10];
    const float* bhh_p  = (const float*)d_in[11];
    const float* Wih_h  = (const float*)d_in[12];
    const float* bih_h  = (const float*)d_in[13];
    const float* bhh_h  = (const float*)d_in[14];
    const float* Wih_m  = (const float*)d_in[15];
    const float* bih_m  = (const float*)d_in[16];
    const float* bhh_m  = (const float*)d_in[17];
    const float* fc_w   = (const float*)d_in[18];
    const float* fc_b   = (const float*)d_in[19];

    float* ws      = (float*)d_ws;
    float* h_s     = ws;                      // 8192*512
    float* h_t     = h_s    + 4194304;        // 8192*512 (reused below)
    float* pre_s   = h_t    + 4194304;
    float* pre_t   = pre_s  + 4194304;
    float* pre_m_h = pre_t  + 4194304;        // 8192*3*512
    // bf16-packed transposed weights alias h_t's buffer: transposes are
    // launched AFTER the last gemm that reads h_t (stream-ordered).
    unsigned* WmT2 = (unsigned*)h_t;          // 256*512 dwords  (0.5 MB)
    unsigned* W3t2 = WmT2 + 131072;           // 256*1536 dwords (1.5 MB)
    float* outp    = (float*)d_out;
    if (ws_size < (size_t)29556736 * 4) return;

    dim3 blk(256);

    // Phase A (parallel)
    gemm3_kernel<64, 3, 0, 1><<<dim3(128, 16), blk, 0, stream>>>(
        embed, premise, 300, Wih_p, 300, 300, bih_p, bhh_p, nullptr, h_s);
    gemm3_kernel<64, 3, 0, 1><<<dim3(128, 16), blk, 0, stream>>>(
        embed, hypothesis, 300, Wih_h, 300, 300, bih_h, bhh_h, nullptr, h_t);
    gemm3_kernel<64, 1, 3, 0><<<dim3(128, 16), blk, 0, stream>>>(
        h_s, nullptr, 512, Ws, 512, 512, nullptr, nullptr, nullptr, pre_s);
    gemm3_kernel<64, 1, 3, 0><<<dim3(128, 16), blk, 0, stream>>>(
        h_t, nullptr, 512, Wt, 512, 512, nullptr, nullptr, nullptr, pre_t);
    gemm3_kernel<64, 3, 1, 0><<<dim3(128, 16), blk, 0, stream>>>(
        h_t, nullptr, 512, Wih_m + 512, 1024, 512, bih_m, bhh_m, nullptr, pre_m_h);

    // Weight transposes (after h_t's last reader; outputs alias h_t space)
    trans_pack_kernel<<<dim3(8, 4, 1), blk, 0, stream>>>(Wm, 512, 0, WmT2, 512);
    trans_pack_kernel<<<dim3(8, 4, 3), blk, 0, stream>>>(Wih_m, 1024, 1, W3t2, 1536);

    // Phase B: 128 independent blocks (one per batch element), no grid sync
    phaseB_kernel<<<dim3(128), dim3(512), 0, stream>>>(
        pre_s, pre_t, h_s, pre_m_h, WmT2, W3t2, w_e, fc_w, fc_b, outp);
}

// Round 9
// 4108.994 us; speedup vs baseline: 9.2391x; 9.2391x over previous
//
#include <hip/hip_runtime.h>

// MatchLSTM forward (Round 9) = Round 8 resubmitted verbatim (Round-8 bench
// died to an infra failure: "MI355X container failed twice"; hypothesis
// untested, so re-run rather than stack changes).
//
// Round-7 counters: WRITE_SIZE 5KB -> 403MB = scratch spills (launch_bounds
// (512,2) capped VGPR at 128; staging arrays needed ~160). This version: VGPR
// ceiling 256 (__launch_bounds__(512), grid=128 blocks -> 1 block/CU anyway),
// wm stages 16x uint4 (64 VGPRs), gates stage 8x uint4 ONE GATE AT A TIME
// (32 VGPRs), outer chunk loops unroll-pinned to stop pressure merging.
//
// Structure: phase B independent per batch element (one block per b, state
// in LDS, no grid sync). Phase A = 5 fp32 tiled GEMMs (unchanged).

#define DEV static __device__ __forceinline__

DEV float fast_sigmoid(float x) { return 1.0f / (1.0f + __expf(-x)); }
DEV float fast_tanh(float x)    { return 1.0f - 2.0f / (__expf(2.0f * x) + 1.0f); }

// bf16 pack/unpack (RTNE pack; unpack = shift into fp32 exponent position)
DEV unsigned f2bf(float x) {
    unsigned v = __float_as_uint(x);
    return (v + 0x7FFFu + ((v >> 16) & 1u)) >> 16;
}
DEV float blo(unsigned u) { return __uint_as_float(u << 16); }
DEV float bhi(unsigned u) { return __uint_as_float(u & 0xFFFF0000u); }

// ---------------------------------------------------------------------------
// Phase A GEMM (unchanged from Round 1; verified passing).
// ---------------------------------------------------------------------------
template<int BM, int NG, int MODE, int GATHER>
__global__ __launch_bounds__(256) void gemm3_kernel(
    const float* __restrict__ A, const int* __restrict__ gidx, int lda,
    const float* __restrict__ W, int ldw, int K,
    const float* __restrict__ bias1, const float* __restrict__ bias2,
    const float* __restrict__ add3, float* __restrict__ out)
{
    constexpr int BK = 32;
    constexpr int TM = BM / 16;
    constexpr int TJ = 2;
    constexpr int AP = BM + 4;
    constexpr int WP = NG * 32 + 4;
    __shared__ __align__(16) float As[BK][AP];
    __shared__ __align__(16) float Wsh[BK][WP];

    const int tid = threadIdx.x;
    const int ty = tid >> 4;
    const int tx = tid & 15;
    const int m0 = blockIdx.x * BM;
    const int j0 = blockIdx.y * 32;

    float acc[TM][TJ][NG];
#pragma unroll
    for (int im = 0; im < TM; ++im)
#pragma unroll
        for (int ij = 0; ij < TJ; ++ij)
#pragma unroll
            for (int g = 0; g < NG; ++g) acc[im][ij][g] = 0.0f;

    for (int k0 = 0; k0 < K; k0 += BK) {
#pragma unroll
        for (int i = tid; i < BM * BK; i += 256) {
            int r = i >> 5, c = i & 31;
            int gk = k0 + c;
            float v = 0.0f;
            if (gk < K) {
                int arow = GATHER ? gidx[m0 + r] : (m0 + r);
                v = A[arow * lda + gk];
            }
            As[c][r] = v;
        }
#pragma unroll
        for (int i = tid; i < NG * 32 * BK; i += 256) {
            int rl = i >> 5, c = i & 31;
            int g = rl >> 5, jj = rl & 31;
            int row = (g == 0 ? 0 : (g == 1 ? 1024 : 1536)) + j0 + jj;
            int gk = k0 + c;
            float v = (gk < K) ? W[row * ldw + gk] : 0.0f;
            Wsh[c][rl] = v;
        }
        __syncthreads();
#pragma unroll
        for (int kk = 0; kk < BK; ++kk) {
            float av[TM];
            if constexpr (TM == 4) {
                float4 t4 = *reinterpret_cast<const float4*>(&As[kk][ty * 4]);
                av[0] = t4.x; av[1] = t4.y; av[2] = t4.z; av[3] = t4.w;
            } else {
                float2 t2 = *reinterpret_cast<const float2*>(&As[kk][ty * 2]);
                av[0] = t2.x; av[1] = t2.y;
            }
#pragma unroll
            for (int g = 0; g < NG; ++g) {
                float2 w2 = *reinterpret_cast<const float2*>(&Wsh[kk][g * 32 + tx * 2]);
#pragma unroll
                for (int im = 0; im < TM; ++im) {
                    acc[im][0][g] += av[im] * w2.x;
                    acc[im][1][g] += av[im] * w2.y;
                }
            }
        }
        __syncthreads();
    }

#pragma unroll
    for (int im = 0; im < TM; ++im) {
        int m = m0 + ty * TM + im;
#pragma unroll
        for (int ij = 0; ij < TJ; ++ij) {
            int j = j0 + tx * TJ + ij;
            if constexpr (MODE == 3) {
                out[m * 512 + j] = acc[im][ij][0];
            } else if constexpr (MODE == 1) {
                out[(m * 3 + 0) * 512 + j] = acc[im][ij][0] + bias1[j] + bias2[j];
                out[(m * 3 + 1) * 512 + j] = acc[im][ij][1] + bias1[1024 + j] + bias2[1024 + j];
                out[(m * 3 + 2) * 512 + j] = acc[im][ij][2] + bias1[1536 + j] + bias2[1536 + j];
            } else if constexpr (MODE == 0) {
                float gi = acc[im][ij][0] + bias1[j] + bias2[j];
                float gg = acc[im][ij][1] + bias1[1024 + j] + bias2[1024 + j];
                float go = acc[im][ij][2] + bias1[1536 + j] + bias2[1536 + j];
                float c  = fast_sigmoid(gi) * fast_tanh(gg);
                out[m * 512 + j] = fast_sigmoid(go) * fast_tanh(c);
            } else {
                float gi = acc[im][ij][0] + add3[(m * 3 + 0) * 512 + j];
                float gg = acc[im][ij][1] + add3[(m * 3 + 1) * 512 + j];
                float go = acc[im][ij][2] + add3[(m * 3 + 2) * 512 + j];
                float c  = fast_sigmoid(gi) * fast_tanh(gg);
                out[m * 512 + j] = fast_sigmoid(go) * fast_tanh(c);
            }
        }
    }
}

// ---------------------------------------------------------------------------
// Transpose + bf16-pack into uint4 layout (verified Round 7, absmax 9.8e-4):
//   uint4 Wpk[h/8][cols]; [hq][col] packs W[col][8hq..8hq+7] as 4 bf16-pair
//   dwords. dword index for pair q=(h/2), col: (q>>2)*(4*out_ld)+4*col+(q&3).
// ---------------------------------------------------------------------------
__global__ __launch_bounds__(256) void trans_pack_kernel(
    const float* __restrict__ W, int ld, int gates,
    unsigned* __restrict__ out, int out_ld)
{
    __shared__ float tile[64][129];
    const int j0 = blockIdx.x * 64;
    const int h0 = blockIdx.y * 128;
    const int g  = blockIdx.z;
    const int row_base = gates ? (g == 0 ? 0 : (g == 1 ? 1024 : 1536)) : 0;
    const int out_col  = gates ? g * 512 : 0;

    for (int i = threadIdx.x; i < 64 * 128; i += 256) {
        int jj = i >> 7, hh = i & 127;
        tile[jj][hh] = W[(size_t)(row_base + j0 + jj) * ld + h0 + hh];
    }
    __syncthreads();
    for (int i = threadIdx.x; i < 4096; i += 256) {
        int jj = i & 63, q = i >> 6;
        int gq = h0 / 2 + q;
        unsigned lo = f2bf(tile[jj][2 * q]);
        unsigned hi = f2bf(tile[jj][2 * q + 1]);
        int col = out_col + j0 + jj;
        out[(size_t)(gq >> 2) * (4 * out_ld) + 4 * col + (gq & 3)] = lo | (hi << 16);
    }
}

// 8-deep staged bf16 GEMV segment: acc += sum over hq-chunk of W.col dot v
DEV float gemv_bf16_512(const uint4* wp, size_t stride, const float* v)
{
    float acc = 0.0f;
#pragma unroll 1
    for (int c0 = 0; c0 < 64; c0 += 8) {
        uint4 u[8];
#pragma unroll
        for (int z = 0; z < 8; ++z) u[z] = wp[(size_t)(c0 + z) * stride];
#pragma unroll
        for (int z = 0; z < 8; ++z) {
            float4 vA = *(const float4*)&v[(c0 + z) * 8];
            float4 vB = *(const float4*)&v[(c0 + z) * 8 + 4];
            acc += blo(u[z].x) * vA.x + bhi(u[z].x) * vA.y
                 + blo(u[z].y) * vA.z + bhi(u[z].y) * vA.w
                 + blo(u[z].z) * vB.x + bhi(u[z].z) * vB.y
                 + blo(u[z].w) * vB.z + bhi(u[z].w) * vB.w;
        }
    }
    return acc;
}

// ---------------------------------------------------------------------------
// Phase B: one block per batch element b, 512 threads, 64 steps, NO grid sync.
// ---------------------------------------------------------------------------
__global__ __launch_bounds__(512) void phaseB_kernel(
    const float* __restrict__ pre_s, const float* __restrict__ pre_t,
    const float* __restrict__ h_s,   const float* __restrict__ pre_m_h,
    const unsigned* __restrict__ WmT2, const unsigned* __restrict__ W3t2,
    const float* __restrict__ w_e,
    const float* __restrict__ fc_w,  const float* __restrict__ fc_b,
    float* __restrict__ out)
{
    __shared__ __align__(16) float hm[512];
    __shared__ __align__(16) float av[512];
    __shared__ __align__(16) float base[512];
    __shared__ __align__(16) float wesh[512];
    __shared__ __align__(16) float sc[64];

    const int b    = blockIdx.x;
    const int tid  = threadIdx.x;          // 0..511
    const int wv   = tid >> 6;             // 0..7
    const int lane = tid & 63;

    wesh[tid] = w_e[tid];
    hm[tid]   = 0.0f;
    __syncthreads();

    const uint4* wpm = (const uint4*)WmT2 + tid;   // [64][512]  uint4 view
    const uint4* wp3 = (const uint4*)W3t2 + tid;   // [64][1536] uint4 view

    for (int k = 0; k < 64; ++k) {
        // ---- wm[j=tid] = hm . Wm[j,:]  (uint4 bf16, 16-deep staging) ----
        float wmj = 0.0f;
        if (k > 0) {
#pragma unroll 1
            for (int c0 = 0; c0 < 64; c0 += 16) {
                uint4 u[16];
#pragma unroll
                for (int z = 0; z < 16; ++z) u[z] = wpm[(size_t)(c0 + z) * 512];
#pragma unroll
                for (int z = 0; z < 16; ++z) {
                    float4 hA = *(const float4*)&hm[(c0 + z) * 8];
                    float4 hB = *(const float4*)&hm[(c0 + z) * 8 + 4];
                    wmj += blo(u[z].x) * hA.x + bhi(u[z].x) * hA.y
                         + blo(u[z].y) * hA.z + bhi(u[z].y) * hA.w
                         + blo(u[z].z) * hB.x + bhi(u[z].z) * hB.y
                         + blo(u[z].w) * hB.z + bhi(u[z].w) * hB.w;
                }
            }
        }
        base[tid] = pre_t[((size_t)k * 128 + b) * 512 + tid] + wmj;
        __syncthreads();

        // ---- scores[t] = sum_h w_e[h] * tanh(pre_s[t,b,h] + base[h]) ----
        for (int tt = 0; tt < 8; ++tt) {
            int t = wv * 8 + tt;
            const float* ps = pre_s + ((size_t)t * 128 + b) * 512;
            float p = 0.0f;
#pragma unroll
            for (int u = 0; u < 8; ++u) {
                int h = lane + 64 * u;
                p += wesh[h] * fast_tanh(ps[h] + base[h]);
            }
#pragma unroll
            for (int off = 32; off; off >>= 1) p += __shfl_xor(p, off);
            if (lane == 0) sc[t] = p;
        }
        __syncthreads();
        if (wv == 0) {                      // softmax over 64 t
            float s = sc[lane], mx = s;
#pragma unroll
            for (int off = 32; off; off >>= 1) mx = fmaxf(mx, __shfl_xor(mx, off));
            float e = __expf(s - mx), sum = e;
#pragma unroll
            for (int off = 32; off; off >>= 1) sum += __shfl_xor(sum, off);
            sc[lane] = e / sum;
        }
        __syncthreads();

        // ---- a[h=tid] = sum_t alpha[t] * h_s[t,b,h] ----
        {
            float aacc = 0.0f;
            const float* hp = h_s + (size_t)b * 512 + tid;
#pragma unroll
            for (int t4 = 0; t4 < 16; ++t4) {
                float4 s4 = *(const float4*)&sc[t4 * 4];
                aacc += s4.x * hp[(size_t)(t4 * 4 + 0) * 65536]
                      + s4.y * hp[(size_t)(t4 * 4 + 1) * 65536]
                      + s4.z * hp[(size_t)(t4 * 4 + 2) * 65536]
                      + s4.w * hp[(size_t)(t4 * 4 + 3) * 65536];
            }
            av[tid] = aacc;
        }
        __syncthreads();

        // ---- gates (one gate at a time, 8-deep staging each) ----
        float gi = gemv_bf16_512(wp3,        1536, av);
        float gg = gemv_bf16_512(wp3 + 512,  1536, av);
        float go = gemv_bf16_512(wp3 + 1024, 1536, av);

        const size_t m = (size_t)k * 128 + b;
        gi += pre_m_h[(m * 3 + 0) * 512 + tid];
        gg += pre_m_h[(m * 3 + 1) * 512 + tid];
        go += pre_m_h[(m * 3 + 2) * 512 + tid];
        float cc   = fast_sigmoid(gi) * fast_tanh(gg);
        float hnew = fast_sigmoid(go) * fast_tanh(cc);
        __syncthreads();
        hm[tid] = hnew;
        __syncthreads();
    }

    // ---- FC epilogue: out[b,c] = hm . fc_w[c] + fc_b[c], waves 0..2 ----
    if (wv < 3) {
        float p = 0.0f;
#pragma unroll
        for (int u = 0; u < 8; ++u) {
            int h = lane + 64 * u;
            p += hm[h] * fc_w[wv * 512 + h];
        }
#pragma unroll
        for (int off = 32; off; off >>= 1) p += __shfl_xor(p, off);
        if (lane == 0) out[b * 3 + wv] = p + fc_b[wv];
    }
}

extern "C" void kernel_launch(void* const* d_in, const int* in_sizes, int n_in,
                              void* d_out, int out_size, void* d_ws, size_t ws_size,
                              hipStream_t stream)
{
    (void)in_sizes; (void)n_in; (void)out_size;
    const int*   premise    = (const int*)d_in[0];
    const int*   hypothesis = (const int*)d_in[2];
    const float* embed  = (const float*)d_in[4];
    const float* w_e    = (const float*)d_in[5];
    const float* Ws     = (const float*)d_in[6];
    const float* Wt     = (const float*)d_in[7];
    const float* Wm     = (const float*)d_in[8];
    const float* Wih_p  = (const float*)d_in[9];
    const float* bih_p  = (const float*)d_in[10];
    const float* bhh_p  = (const float*)d_in[11];
    const float* Wih_h  = (const float*)d_in[12];
    const float* bih_h  = (const float*)d_in[13];
    const float* bhh_h  = (const float*)d_in[14];
    const float* Wih_m  = (const float*)d_in[15];
    const float* bih_m  = (const float*)d_in[16];
    const float* bhh_m  = (const float*)d_in[17];
    const float* fc_w   = (const float*)d_in[18];
    const float* fc_b   = (const float*)d_in[19];

    float* ws      = (float*)d_ws;
    float* h_s     = ws;                      // 8192*512
    float* h_t     = h_s    + 4194304;        // 8192*512 (reused below)
    float* pre_s   = h_t    + 4194304;
    float* pre_t   = pre_s  + 4194304;
    float* pre_m_h = pre_t  + 4194304;        // 8192*3*512
    // bf16-packed transposed weights alias h_t's buffer: transposes are
    // launched AFTER the last gemm that reads h_t (stream-ordered).
    unsigned* WmT2 = (unsigned*)h_t;          // 256*512 dwords  (0.5 MB)
    unsigned* W3t2 = WmT2 + 131072;           // 256*1536 dwords (1.5 MB)
    float* outp    = (float*)d_out;
    if (ws_size < (size_t)29556736 * 4) return;

    dim3 blk(256);

    // Phase A (parallel)
    gemm3_kernel<64, 3, 0, 1><<<dim3(128, 16), blk, 0, stream>>>(
        embed, premise, 300, Wih_p, 300, 300, bih_p, bhh_p, nullptr, h_s);
    gemm3_kernel<64, 3, 0, 1><<<dim3(128, 16), blk, 0, stream>>>(
        embed, hypothesis, 300, Wih_h, 300, 300, bih_h, bhh_h, nullptr, h_t);
    gemm3_kernel<64, 1, 3, 0><<<dim3(128, 16), blk, 0, stream>>>(
        h_s, nullptr, 512, Ws, 512, 512, nullptr, nullptr, nullptr, pre_s);
    gemm3_kernel<64, 1, 3, 0><<<dim3(128, 16), blk, 0, stream>>>(
        h_t, nullptr, 512, Wt, 512, 512, nullptr, nullptr, nullptr, pre_t);
    gemm3_kernel<64, 3, 1, 0><<<dim3(128, 16), blk, 0, stream>>>(
        h_t, nullptr, 512, Wih_m + 512, 1024, 512, bih_m, bhh_m, nullptr, pre_m_h);

    // Weight transposes (after h_t's last reader; outputs alias h_t space)
    trans_pack_kernel<<<dim3(8, 4, 1), blk, 0, stream>>>(Wm, 512, 0, WmT2, 512);
    trans_pack_kernel<<<dim3(8, 4, 3), blk, 0, stream>>>(Wih_m, 1024, 1, W3t2, 1536);

    // Phase B: 128 independent blocks (one per batch element), no grid sync
    phaseB_kernel<<<dim3(128), dim3(512), 0, stream>>>(
        pre_s, pre_t, h_s, pre_m_h, WmT2, W3t2, w_e, fc_w, fc_b, outp);
}

// Round 10
// 2778.187 us; speedup vs baseline: 13.6647x; 1.4790x over previous
//
#include <hip/hip_runtime.h>

// MatchLSTM forward (Round 10).
// Round-9 counters: phaseB 49 us/step, VALUBusy 23.8%, occupancy 11.9%
// (2 waves/SIMD) -> still ~76% stall; VALU-busy time matches the op-count
// floor (~11 us/step). Fix: 1024 threads/block, every phase K-split across
// two thread-halves (LDS partial reduction) -> 4 waves/SIMD + halved serial
// chains; nontemporal loads on streamed activations (pre_s/h_s/pre_t/
// pre_m_h) so the per-step weight streams stay L2-resident.
//
// Structure: phase B independent per batch element (one block per b, state
// in LDS, no grid sync). Phase A = 5 fp32 tiled GEMMs (unchanged).

#define DEV static __device__ __forceinline__

DEV float fast_sigmoid(float x) { return 1.0f / (1.0f + __expf(-x)); }
DEV float fast_tanh(float x)    { return 1.0f - 2.0f / (__expf(2.0f * x) + 1.0f); }

// bf16 pack/unpack (RTNE pack; unpack = shift into fp32 exponent position)
DEV unsigned f2bf(float x) {
    unsigned v = __float_as_uint(x);
    return (v + 0x7FFFu + ((v >> 16) & 1u)) >> 16;
}
DEV float blo(unsigned u) { return __uint_as_float(u << 16); }
DEV float bhi(unsigned u) { return __uint_as_float(u & 0xFFFF0000u); }

DEV float ntload(const float* p) { return __builtin_nontemporal_load(p); }

// ---------------------------------------------------------------------------
// Phase A GEMM (unchanged from Round 1; verified passing).
// ---------------------------------------------------------------------------
template<int BM, int NG, int MODE, int GATHER>
__global__ __launch_bounds__(256) void gemm3_kernel(
    const float* __restrict__ A, const int* __restrict__ gidx, int lda,
    const float* __restrict__ W, int ldw, int K,
    const float* __restrict__ bias1, const float* __restrict__ bias2,
    const float* __restrict__ add3, float* __restrict__ out)
{
    constexpr int BK = 32;
    constexpr int TM = BM / 16;
    constexpr int TJ = 2;
    constexpr int AP = BM + 4;
    constexpr int WP = NG * 32 + 4;
    __shared__ __align__(16) float As[BK][AP];
    __shared__ __align__(16) float Wsh[BK][WP];

    const int tid = threadIdx.x;
    const int ty = tid >> 4;
    const int tx = tid & 15;
    const int m0 = blockIdx.x * BM;
    const int j0 = blockIdx.y * 32;

    float acc[TM][TJ][NG];
#pragma unroll
    for (int im = 0; im < TM; ++im)
#pragma unroll
        for (int ij = 0; ij < TJ; ++ij)
#pragma unroll
            for (int g = 0; g < NG; ++g) acc[im][ij][g] = 0.0f;

    for (int k0 = 0; k0 < K; k0 += BK) {
#pragma unroll
        for (int i = tid; i < BM * BK; i += 256) {
            int r = i >> 5, c = i & 31;
            int gk = k0 + c;
            float v = 0.0f;
            if (gk < K) {
                int arow = GATHER ? gidx[m0 + r] : (m0 + r);
                v = A[arow * lda + gk];
            }
            As[c][r] = v;
        }
#pragma unroll
        for (int i = tid; i < NG * 32 * BK; i += 256) {
            int rl = i >> 5, c = i & 31;
            int g = rl >> 5, jj = rl & 31;
            int row = (g == 0 ? 0 : (g == 1 ? 1024 : 1536)) + j0 + jj;
            int gk = k0 + c;
            float v = (gk < K) ? W[row * ldw + gk] : 0.0f;
            Wsh[c][rl] = v;
        }
        __syncthreads();
#pragma unroll
        for (int kk = 0; kk < BK; ++kk) {
            float av[TM];
            if constexpr (TM == 4) {
                float4 t4 = *reinterpret_cast<const float4*>(&As[kk][ty * 4]);
                av[0] = t4.x; av[1] = t4.y; av[2] = t4.z; av[3] = t4.w;
            } else {
                float2 t2 = *reinterpret_cast<const float2*>(&As[kk][ty * 2]);
                av[0] = t2.x; av[1] = t2.y;
            }
#pragma unroll
            for (int g = 0; g < NG; ++g) {
                float2 w2 = *reinterpret_cast<const float2*>(&Wsh[kk][g * 32 + tx * 2]);
#pragma unroll
                for (int im = 0; im < TM; ++im) {
                    acc[im][0][g] += av[im] * w2.x;
                    acc[im][1][g] += av[im] * w2.y;
                }
            }
        }
        __syncthreads();
    }

#pragma unroll
    for (int im = 0; im < TM; ++im) {
        int m = m0 + ty * TM + im;
#pragma unroll
        for (int ij = 0; ij < TJ; ++ij) {
            int j = j0 + tx * TJ + ij;
            if constexpr (MODE == 3) {
                out[m * 512 + j] = acc[im][ij][0];
            } else if constexpr (MODE == 1) {
                out[(m * 3 + 0) * 512 + j] = acc[im][ij][0] + bias1[j] + bias2[j];
                out[(m * 3 + 1) * 512 + j] = acc[im][ij][1] + bias1[1024 + j] + bias2[1024 + j];
                out[(m * 3 + 2) * 512 + j] = acc[im][ij][2] + bias1[1536 + j] + bias2[1536 + j];
            } else if constexpr (MODE == 0) {
                float gi = acc[im][ij][0] + bias1[j] + bias2[j];
                float gg = acc[im][ij][1] + bias1[1024 + j] + bias2[1024 + j];
                float go = acc[im][ij][2] + bias1[1536 + j] + bias2[1536 + j];
                float c  = fast_sigmoid(gi) * fast_tanh(gg);
                out[m * 512 + j] = fast_sigmoid(go) * fast_tanh(c);
            } else {
                float gi = acc[im][ij][0] + add3[(m * 3 + 0) * 512 + j];
                float gg = acc[im][ij][1] + add3[(m * 3 + 1) * 512 + j];
                float go = acc[im][ij][2] + add3[(m * 3 + 2) * 512 + j];
                float c  = fast_sigmoid(gi) * fast_tanh(gg);
                out[m * 512 + j] = fast_sigmoid(go) * fast_tanh(c);
            }
        }
    }
}

// ---------------------------------------------------------------------------
// Transpose + bf16-pack into uint4 layout (verified, absmax 9.8e-4):
//   uint4 Wpk[h/8][cols]; [hq][col] packs W[col][8hq..8hq+7] as 4 bf16-pair
//   dwords. dword index for pair q=(h/2), col: (q>>2)*(4*out_ld)+4*col+(q&3).
// ---------------------------------------------------------------------------
__global__ __launch_bounds__(256) void trans_pack_kernel(
    const float* __restrict__ W, int ld, int gates,
    unsigned* __restrict__ out, int out_ld)
{
    __shared__ float tile[64][129];
    const int j0 = blockIdx.x * 64;
    const int h0 = blockIdx.y * 128;
    const int g  = blockIdx.z;
    const int row_base = gates ? (g == 0 ? 0 : (g == 1 ? 1024 : 1536)) : 0;
    const int out_col  = gates ? g * 512 : 0;

    for (int i = threadIdx.x; i < 64 * 128; i += 256) {
        int jj = i >> 7, hh = i & 127;
        tile[jj][hh] = W[(size_t)(row_base + j0 + jj) * ld + h0 + hh];
    }
    __syncthreads();
    for (int i = threadIdx.x; i < 4096; i += 256) {
        int jj = i & 63, q = i >> 6;
        int gq = h0 / 2 + q;
        unsigned lo = f2bf(tile[jj][2 * q]);
        unsigned hi = f2bf(tile[jj][2 * q + 1]);
        int col = out_col + j0 + jj;
        out[(size_t)(gq >> 2) * (4 * out_ld) + 4 * col + (gq & 3)] = lo | (hi << 16);
    }
}

// ---------------------------------------------------------------------------
// Phase B: one block per batch element b, 1024 threads, 64 steps, no grid
// sync. Thread = (kh = tid>>9, j = tid&511); every GEMV is K-split across
// the two halves with an LDS partial reduction.
// ---------------------------------------------------------------------------
__global__ __launch_bounds__(1024) void phaseB_kernel(
    const float* __restrict__ pre_s, const float* __restrict__ pre_t,
    const float* __restrict__ h_s,   const float* __restrict__ pre_m_h,
    const unsigned* __restrict__ WmT2, const unsigned* __restrict__ W3t2,
    const float* __restrict__ w_e,
    const float* __restrict__ fc_w,  const float* __restrict__ fc_b,
    float* __restrict__ out)
{
    __shared__ __align__(16) float hm[512];
    __shared__ __align__(16) float av[512];
    __shared__ __align__(16) float base[512];
    __shared__ __align__(16) float wesh[512];
    __shared__ __align__(16) float sc[64];
    __shared__ __align__(16) float red[2 * 512];       //  4 KB
    __shared__ __align__(16) float red3[3 * 2 * 512];  // 12 KB

    const int b    = blockIdx.x;
    const int tid  = threadIdx.x;          // 0..1023
    const int wv   = tid >> 6;             // 0..15
    const int lane = tid & 63;
    const int j    = tid & 511;            // output column
    const int kh   = tid >> 9;             // K-half (0/1)
    const int hq0  = kh * 32;              // this half's packed-row base

    if (tid < 512) { wesh[tid] = w_e[tid]; hm[tid] = 0.0f; }
    __syncthreads();

    const uint4* wpm = (const uint4*)WmT2 + j;   // [64][512]  uint4 view
    const uint4* wp3 = (const uint4*)W3t2 + j;   // [64][1536] uint4 view

    for (int k = 0; k < 64; ++k) {
        // ---- wm partials: red[kh][j] = hm[khalf] . Wm[j][khalf] ----
        if (k > 0) {
            float p = 0.0f;
#pragma unroll 1
            for (int c0 = 0; c0 < 32; c0 += 8) {
                uint4 u[8];
#pragma unroll
                for (int z = 0; z < 8; ++z) u[z] = wpm[(size_t)(hq0 + c0 + z) * 512];
#pragma unroll
                for (int z = 0; z < 8; ++z) {
                    const float* hv = &hm[(hq0 + c0 + z) * 8];
                    float4 vA = *(const float4*)hv;
                    float4 vB = *(const float4*)(hv + 4);
                    p += blo(u[z].x) * vA.x + bhi(u[z].x) * vA.y
                       + blo(u[z].y) * vA.z + bhi(u[z].y) * vA.w
                       + blo(u[z].z) * vB.x + bhi(u[z].z) * vB.y
                       + blo(u[z].w) * vB.z + bhi(u[z].w) * vB.w;
                }
            }
            red[kh * 512 + j] = p;
        }
        __syncthreads();
        if (tid < 512) {
            float wmj = (k > 0) ? (red[tid] + red[512 + tid]) : 0.0f;
            base[tid] = ntload(&pre_t[((size_t)k * 128 + b) * 512 + tid]) + wmj;
        }
        __syncthreads();

        // ---- scores: wave wv handles t = wv*4 .. wv*4+3 ----
#pragma unroll
        for (int tt = 0; tt < 4; ++tt) {
            int t = wv * 4 + tt;
            const float* ps = pre_s + ((size_t)t * 128 + b) * 512;
            float p = 0.0f;
#pragma unroll
            for (int u = 0; u < 8; ++u) {
                int h = lane + 64 * u;
                p += wesh[h] * fast_tanh(ntload(&ps[h]) + base[h]);
            }
#pragma unroll
            for (int off = 32; off; off >>= 1) p += __shfl_xor(p, off);
            if (lane == 0) sc[t] = p;
        }
        __syncthreads();
        if (wv == 0) {                      // softmax over 64 t
            float s = sc[lane], mx = s;
#pragma unroll
            for (int off = 32; off; off >>= 1) mx = fmaxf(mx, __shfl_xor(mx, off));
            float e = __expf(s - mx), sum = e;
#pragma unroll
            for (int off = 32; off; off >>= 1) sum += __shfl_xor(sum, off);
            sc[lane] = e / sum;
        }
        __syncthreads();

        // ---- a partials: red[kh][h] = sum over t-half of alpha*h_s ----
        {
            const float* hp = h_s + (size_t)b * 512 + j;
            float p = 0.0f;
#pragma unroll
            for (int t4 = 0; t4 < 8; ++t4) {
                int t = kh * 32 + t4 * 4;
                float4 s4 = *(const float4*)&sc[t];
                p += s4.x * ntload(&hp[(size_t)(t + 0) * 65536])
                   + s4.y * ntload(&hp[(size_t)(t + 1) * 65536])
                   + s4.z * ntload(&hp[(size_t)(t + 2) * 65536])
                   + s4.w * ntload(&hp[(size_t)(t + 3) * 65536]);
            }
            red[kh * 512 + j] = p;
        }
        __syncthreads();
        if (tid < 512) av[tid] = red[tid] + red[512 + tid];
        __syncthreads();

        // ---- gates partials: red3[g][kh][j] ----
#pragma unroll 1
        for (int g = 0; g < 3; ++g) {
            const uint4* wg = wp3 + g * 512;
            float p = 0.0f;
#pragma unroll 1
            for (int c0 = 0; c0 < 32; c0 += 8) {
                uint4 u[8];
#pragma unroll
                for (int z = 0; z < 8; ++z) u[z] = wg[(size_t)(hq0 + c0 + z) * 1536];
#pragma unroll
                for (int z = 0; z < 8; ++z) {
                    const float* vv = &av[(hq0 + c0 + z) * 8];
                    float4 vA = *(const float4*)vv;
                    float4 vB = *(const float4*)(vv + 4);
                    p += blo(u[z].x) * vA.x + bhi(u[z].x) * vA.y
                       + blo(u[z].y) * vA.z + bhi(u[z].y) * vA.w
                       + blo(u[z].z) * vB.x + bhi(u[z].z) * vB.y
                       + blo(u[z].w) * vB.z + bhi(u[z].w) * vB.w;
                }
            }
            red3[(g * 2 + kh) * 512 + j] = p;
        }
        __syncthreads();
        if (tid < 512) {
            const size_t m = (size_t)k * 128 + b;
            float gi = red3[tid]        + red3[512 + tid]
                     + ntload(&pre_m_h[(m * 3 + 0) * 512 + tid]);
            float gg = red3[1024 + tid] + red3[1536 + tid]
                     + ntload(&pre_m_h[(m * 3 + 1) * 512 + tid]);
            float go = red3[2048 + tid] + red3[2560 + tid]
                     + ntload(&pre_m_h[(m * 3 + 2) * 512 + tid]);
            float cc = fast_sigmoid(gi) * fast_tanh(gg);
            hm[tid]  = fast_sigmoid(go) * fast_tanh(cc);
        }
        __syncthreads();
    }

    // ---- FC epilogue: out[b,c] = hm . fc_w[c] + fc_b[c], waves 0..2 ----
    if (wv < 3) {
        float p = 0.0f;
#pragma unroll
        for (int u = 0; u < 8; ++u) {
            int h = lane + 64 * u;
            p += hm[h] * fc_w[wv * 512 + h];
        }
#pragma unroll
        for (int off = 32; off; off >>= 1) p += __shfl_xor(p, off);
        if (lane == 0) out[b * 3 + wv] = p + fc_b[wv];
    }
}

extern "C" void kernel_launch(void* const* d_in, const int* in_sizes, int n_in,
                              void* d_out, int out_size, void* d_ws, size_t ws_size,
                              hipStream_t stream)
{
    (void)in_sizes; (void)n_in; (void)out_size;
    const int*   premise    = (const int*)d_in[0];
    const int*   hypothesis = (const int*)d_in[2];
    const float* embed  = (const float*)d_in[4];
    const float* w_e    = (const float*)d_in[5];
    const float* Ws     = (const float*)d_in[6];
    const float* Wt     = (const float*)d_in[7];
    const float* Wm     = (const float*)d_in[8];
    const float* Wih_p  = (const float*)d_in[9];
    const float* bih_p  = (const float*)d_in[10];
    const float* bhh_p  = (const float*)d_in[11];
    const float* Wih_h  = (const float*)d_in[12];
    const float* bih_h  = (const float*)d_in[13];
    const float* bhh_h  = (const float*)d_in[14];
    const float* Wih_m  = (const float*)d_in[15];
    const float* bih_m  = (const float*)d_in[16];
    const float* bhh_m  = (const float*)d_in[17];
    const float* fc_w   = (const float*)d_in[18];
    const float* fc_b   = (const float*)d_in[19];

    float* ws      = (float*)d_ws;
    float* h_s     = ws;                      // 8192*512
    float* h_t     = h_s    + 4194304;        // 8192*512 (reused below)
    float* pre_s   = h_t    + 4194304;
    float* pre_t   = pre_s  + 4194304;
    float* pre_m_h = pre_t  + 4194304;        // 8192*3*512
    // bf16-packed transposed weights alias h_t's buffer: transposes are
    // launched AFTER the last gemm that reads h_t (stream-ordered).
    unsigned* WmT2 = (unsigned*)h_t;          // 256*512 dwords  (0.5 MB)
    unsigned* W3t2 = WmT2 + 131072;           // 256*1536 dwords (1.5 MB)
    float* outp    = (float*)d_out;
    if (ws_size < (size_t)29556736 * 4) return;

    dim3 blk(256);

    // Phase A (parallel)
    gemm3_kernel<64, 3, 0, 1><<<dim3(128, 16), blk, 0, stream>>>(
        embed, premise, 300, Wih_p, 300, 300, bih_p, bhh_p, nullptr, h_s);
    gemm3_kernel<64, 3, 0, 1><<<dim3(128, 16), blk, 0, stream>>>(
        embed, hypothesis, 300, Wih_h, 300, 300, bih_h, bhh_h, nullptr, h_t);
    gemm3_kernel<64, 1, 3, 0><<<dim3(128, 16), blk, 0, stream>>>(
        h_s, nullptr, 512, Ws, 512, 512, nullptr, nullptr, nullptr, pre_s);
    gemm3_kernel<64, 1, 3, 0><<<dim3(128, 16), blk, 0, stream>>>(
        h_t, nullptr, 512, Wt, 512, 512, nullptr, nullptr, nullptr, pre_t);
    gemm3_kernel<64, 3, 1, 0><<<dim3(128, 16), blk, 0, stream>>>(
        h_t, nullptr, 512, Wih_m + 512, 1024, 512, bih_m, bhh_m, nullptr, pre_m_h);

    // Weight transposes (after h_t's last reader; outputs alias h_t space)
    trans_pack_kernel<<<dim3(8, 4, 1), blk, 0, stream>>>(Wm, 512, 0, WmT2, 512);
    trans_pack_kernel<<<dim3(8, 4, 3), blk, 0, stream>>>(Wih_m, 1024, 1, W3t2, 1536);

    // Phase B: 128 independent blocks (one per batch element), no grid sync
    phaseB_kernel<<<dim3(128), dim3(1024), 0, stream>>>(
        pre_s, pre_t, h_s, pre_m_h, WmT2, W3t2, w_e, fc_w, fc_b, outp);
}